// Round 5
// baseline (128.277 us; speedup 1.0000x reference)
//
#include <hip/hip_runtime.h>

typedef float v2f __attribute__((ext_vector_type(2)));

#define MPTS 8192          // pc points per batch
#define NVERT 8192         // mesh vertices per batch
#define TPB 256
#define PPT 16             // points per thread (high arith intensity per LDS read)
#define BQ (TPB*PPT)       // 4096 points per block
#define NCHUNK 64
#define VC (NVERT/NCHUNK)  // 128 vertices per chunk
#define VPAIRS (VC/2)      // 64 vertex pairs in LDS (2 KB)

// Kernel 1: per-point min of t = |v|^2 - 2 p.v over one 128-vertex chunk.
// Vertices staged in LDS as pairs; all lanes read the same LDS address
// (broadcast, conflict-free). Per vertex-pair per point: 3 v_pk_fma_f32 +
// packed min -> VALU-bound at PPT=16 (128 VALU-cyc vs ~24 LDS-cyc per pair).
__global__ __launch_bounds__(TPB, 2) void minpart_kernel(
        const float* __restrict__ vert,    // [B,3,NVERT]
        const float* __restrict__ pc,      // [B,3,MPTS]
        float* __restrict__ partial)       // [B,NCHUNK,MPTS]
{
    __shared__ float4 lvA[VPAIRS];  // (x0,x1,y0,y1)
    __shared__ float4 lvB[VPAIRS];  // (z0,z1,w0,w1), w = |v|^2
    const int b = blockIdx.z, chunk = blockIdx.y;
    const int mbase = blockIdx.x * BQ;
    const int tid = threadIdx.x;

    // Stage the 128-vertex chunk (wave 0 only; 2 KB).
    const float* vb = vert + (size_t)b * 3 * NVERT + chunk * VC;
    if (tid < VPAIRS) {
        const v2f x = ((const v2f*)vb)[tid];
        const v2f y = ((const v2f*)(vb + NVERT))[tid];
        const v2f z = ((const v2f*)(vb + 2 * NVERT))[tid];
        const v2f w = x * x + y * y + z * z;
        lvA[tid] = make_float4(x.x, x.y, y.x, y.y);
        lvB[tid] = make_float4(z.x, z.y, w.x, w.y);
    }

    // Per-thread point coefficients (-2p) as packed splats.
    const float* pcb = pc + (size_t)b * 3 * MPTS;
    v2f npx[PPT], npy[PPT], npz[PPT], acc[PPT];
    #pragma unroll
    for (int p = 0; p < PPT; ++p) {
        const int m = mbase + p * TPB + tid;
        const float x = pcb[m], y = pcb[MPTS + m], z = pcb[2 * MPTS + m];
        npx[p] = (v2f){-2.0f * x, -2.0f * x};
        npy[p] = (v2f){-2.0f * y, -2.0f * y};
        npz[p] = (v2f){-2.0f * z, -2.0f * z};
        acc[p] = (v2f){1e30f, 1e30f};
    }
    __syncthreads();

    #pragma unroll 4
    for (int j = 0; j < VPAIRS; ++j) {
        const float4 A = lvA[j], Bv = lvB[j];
        const v2f vx = {A.x, A.y}, vy = {A.z, A.w};
        const v2f vz = {Bv.x, Bv.y}, vw = {Bv.z, Bv.w};
        #pragma unroll
        for (int p = 0; p < PPT; ++p) {
            const v2f t = __builtin_elementwise_fma(npx[p], vx,
                           __builtin_elementwise_fma(npy[p], vy,
                            __builtin_elementwise_fma(npz[p], vz, vw)));
            acc[p] = __builtin_elementwise_min(acc[p], t);
        }
    }

    // One coalesced store per point — no atomics, no ws init needed.
    float* po = partial + ((size_t)b * NCHUNK + chunk) * MPTS + mbase + tid;
    #pragma unroll
    for (int p = 0; p < PPT; ++p)
        po[p * TPB] = fminf(acc[p].x, acc[p].y);
}

// Kernel 2: fold the NCHUNK partial minima per point, add |p|^2, mask
// all-zero columns, per-block (sum,cnt) partials. 8 blocks per batch.
__global__ __launch_bounds__(256) void reduce_kernel(
        const float* __restrict__ pc,
        const float* __restrict__ partial,
        v2f* __restrict__ part)            // [B*8]
{
    const int b = blockIdx.x >> 3, sl = blockIdx.x & 7;
    const int tid = threadIdx.x;
    const float* pcb = pc + (size_t)b * 3 * MPTS;
    const float* pb  = partial + (size_t)b * NCHUNK * MPTS;

    float sum = 0.0f, cnt = 0.0f;
    #pragma unroll
    for (int k = 0; k < 4; ++k) {
        const int m = sl * 1024 + k * 256 + tid;
        float t = pb[m];
        #pragma unroll 8
        for (int c = 1; c < NCHUNK; ++c)
            t = fminf(t, pb[(size_t)c * MPTS + m]);     // coalesced per plane
        const float x = pcb[m], y = pcb[MPTS + m], z = pcb[2 * MPTS + m];
        const float d2 = fmaf(x, x, fmaf(y, y, fmaf(z, z, t)));
        if (!(x == 0.0f && y == 0.0f && z == 0.0f)) { sum += d2; cnt += 1.0f; }
    }
    for (int off = 32; off; off >>= 1) {
        sum += __shfl_down(sum, off);
        cnt += __shfl_down(cnt, off);
    }
    __shared__ float ss[4], sc[4];
    const int wid = tid >> 6, lane = tid & 63;
    if (lane == 0) { ss[wid] = sum; sc[wid] = cnt; }
    __syncthreads();
    if (tid == 0)
        part[blockIdx.x] = (v2f){ss[0] + ss[1] + ss[2] + ss[3],
                                 sc[0] + sc[1] + sc[2] + sc[3]};
}

// Kernel 3: one wave folds 8 partials per batch, then means across batches.
__global__ __launch_bounds__(64) void final_kernel(
        const v2f* __restrict__ part, float* __restrict__ out, int B)
{
    const int lane = threadIdx.x;
    float s = 0.0f, c = 0.0f;
    if (lane < B * 8) { const v2f p = part[lane]; s = p.x; c = p.y; }
    #pragma unroll
    for (int off = 4; off; off >>= 1) {
        s += __shfl_down(s, off);
        c += __shfl_down(c, off);
    }
    const float r = s / c;                 // valid at lane % 8 == 0
    float acc = 0.0f;
    for (int g = 0; g < B; ++g) acc += __shfl(r, g * 8);
    if (lane == 0) out[0] = acc / (float)B;
}

extern "C" void kernel_launch(void* const* d_in, const int* in_sizes, int n_in,
                              void* d_out, int out_size, void* d_ws, size_t ws_size,
                              hipStream_t stream) {
    const float* vert = (const float*)d_in[0];  // [B,3,128,64]
    const float* pc   = (const float*)d_in[1];  // [B,3,8192]
    float* out        = (float*)d_out;
    const int B = in_sizes[0] / (3 * NVERT);

    float* partial = (float*)d_ws;                               // [B,64,MPTS] = 8 MB
    v2f* part = (v2f*)(partial + (size_t)B * NCHUNK * MPTS);     // [B*8]

    dim3 grid(MPTS / BQ, NCHUNK, B);   // 2 x 64 x B = 512 blocks
    minpart_kernel<<<grid, TPB, 0, stream>>>(vert, pc, partial);
    reduce_kernel<<<B * 8, 256, 0, stream>>>(pc, partial, part);
    final_kernel<<<1, 64, 0, stream>>>(part, out, B);
}

// Round 6
// 83.560 us; speedup vs baseline: 1.5351x; 1.5351x over previous
//
#include <hip/hip_runtime.h>

typedef float v2f __attribute__((ext_vector_type(2)));

#define MPTS 8192          // pc points per batch
#define NVERT 8192         // mesh vertices per batch
#define TPB 256
#define PPT 8              // points per thread
#define BQ (TPB*PPT)       // 2048 points per block
#define NCHUNK 32
#define VC (NVERT/NCHUNK)  // 256 vertices per chunk
#define VPAIRS (VC/2)      // 128 vertex pairs in LDS (4 KB)

// Kernel 1: per-point min of t = |v|^2 - 2 p.v over one 256-vertex chunk.
// Vertices staged in LDS as pairs; all lanes read the same LDS address
// (broadcast, conflict-free). Per vertex-pair per point: 3 pk_fma + pk_min.
__global__ __launch_bounds__(TPB, 2) void minpart_kernel(
        const float* __restrict__ vert,    // [B,3,NVERT]
        const float* __restrict__ pc,      // [B,3,MPTS]
        float* __restrict__ partial)       // [B,NCHUNK,MPTS]
{
    __shared__ float4 lvA[VPAIRS];  // (x0,x1,y0,y1)
    __shared__ float4 lvB[VPAIRS];  // (z0,z1,w0,w1), w = |v|^2
    const int b = blockIdx.z, chunk = blockIdx.y;
    const int mbase = blockIdx.x * BQ;
    const int tid = threadIdx.x;

    // Stage the 256-vertex chunk (first 128 threads).
    const float* vb = vert + (size_t)b * 3 * NVERT + chunk * VC;
    if (tid < VPAIRS) {
        const v2f x = ((const v2f*)vb)[tid];
        const v2f y = ((const v2f*)(vb + NVERT))[tid];
        const v2f z = ((const v2f*)(vb + 2 * NVERT))[tid];
        const v2f w = x * x + y * y + z * z;
        lvA[tid] = make_float4(x.x, x.y, y.x, y.y);
        lvB[tid] = make_float4(z.x, z.y, w.x, w.y);
    }

    // Per-thread point coefficients (-2p) as packed splats.
    const float* pcb = pc + (size_t)b * 3 * MPTS;
    v2f npx[PPT], npy[PPT], npz[PPT], acc[PPT];
    #pragma unroll
    for (int p = 0; p < PPT; ++p) {
        const int m = mbase + p * TPB + tid;
        const float x = pcb[m], y = pcb[MPTS + m], z = pcb[2 * MPTS + m];
        npx[p] = (v2f){-2.0f * x, -2.0f * x};
        npy[p] = (v2f){-2.0f * y, -2.0f * y};
        npz[p] = (v2f){-2.0f * z, -2.0f * z};
        acc[p] = (v2f){1e30f, 1e30f};
    }
    __syncthreads();

    #pragma unroll 2
    for (int j = 0; j < VPAIRS; ++j) {
        const float4 A = lvA[j], Bv = lvB[j];
        const v2f vx = {A.x, A.y}, vy = {A.z, A.w};
        const v2f vz = {Bv.x, Bv.y}, vw = {Bv.z, Bv.w};
        #pragma unroll
        for (int p = 0; p < PPT; ++p) {
            const v2f t = __builtin_elementwise_fma(npx[p], vx,
                           __builtin_elementwise_fma(npy[p], vy,
                            __builtin_elementwise_fma(npz[p], vz, vw)));
            acc[p] = __builtin_elementwise_min(acc[p], t);
        }
    }

    // One coalesced store per point — no atomics, no ws init needed.
    float* po = partial + ((size_t)b * NCHUNK + chunk) * MPTS + mbase + tid;
    #pragma unroll
    for (int p = 0; p < PPT; ++p)
        po[p * TPB] = fminf(acc[p].x, acc[p].y);
}

// Kernel 2: fold NCHUNK partial planes per point with float4 loads (32
// independent 16B loads per thread = high MLP), add |p|^2, mask all-zero
// columns, per-block (sum,cnt). Grid = B*32 blocks x 64 threads.
__global__ __launch_bounds__(64) void reduce_kernel(
        const float* __restrict__ pc,
        const float* __restrict__ partial,
        v2f* __restrict__ part)            // [B*32]
{
    const int b = blockIdx.x >> 5, sl = blockIdx.x & 31;
    const int tid = threadIdx.x;
    const int m = sl * 256 + tid * 4;      // 4 consecutive points per thread
    const float* pcb = pc + (size_t)b * 3 * MPTS;
    const float* pb  = partial + (size_t)b * NCHUNK * MPTS;

    float4 t = *(const float4*)(pb + m);
    #pragma unroll 8
    for (int c = 1; c < NCHUNK; ++c) {
        const float4 u = *(const float4*)(pb + (size_t)c * MPTS + m);
        t.x = fminf(t.x, u.x); t.y = fminf(t.y, u.y);
        t.z = fminf(t.z, u.z); t.w = fminf(t.w, u.w);
    }
    const float4 x = *(const float4*)(pcb + m);
    const float4 y = *(const float4*)(pcb + MPTS + m);
    const float4 z = *(const float4*)(pcb + 2 * MPTS + m);

    float sum = 0.0f, cnt = 0.0f;
    {
        const float xs[4] = {x.x, x.y, x.z, x.w};
        const float ys[4] = {y.x, y.y, y.z, y.w};
        const float zs[4] = {z.x, z.y, z.z, z.w};
        const float ts[4] = {t.x, t.y, t.z, t.w};
        #pragma unroll
        for (int i = 0; i < 4; ++i) {
            const float d2 = fmaf(xs[i], xs[i], fmaf(ys[i], ys[i],
                             fmaf(zs[i], zs[i], ts[i])));
            if (!(xs[i] == 0.0f && ys[i] == 0.0f && zs[i] == 0.0f)) {
                sum += d2; cnt += 1.0f;
            }
        }
    }
    #pragma unroll
    for (int off = 32; off; off >>= 1) {
        sum += __shfl_down(sum, off);
        cnt += __shfl_down(cnt, off);
    }
    if (tid == 0) part[blockIdx.x] = (v2f){sum, cnt};
}

// Kernel 3: fold B*32 (sum,cnt) partials -> per-item means -> batch mean.
__global__ __launch_bounds__(128) void final_kernel(
        const v2f* __restrict__ part, float* __restrict__ out, int B)
{
    __shared__ float ss[128], sc[128];
    const int t = threadIdx.x;
    v2f p = (v2f){0.0f, 0.0f};
    if (t < B * 32) p = part[t];
    ss[t] = p.x; sc[t] = p.y;
    __syncthreads();
    if (t == 0) {
        float acc = 0.0f;
        for (int b = 0; b < B; ++b) {
            float s = 0.0f, c = 0.0f;
            for (int i = 0; i < 32; ++i) { s += ss[b * 32 + i]; c += sc[b * 32 + i]; }
            acc += s / c;
        }
        out[0] = acc / (float)B;
    }
}

extern "C" void kernel_launch(void* const* d_in, const int* in_sizes, int n_in,
                              void* d_out, int out_size, void* d_ws, size_t ws_size,
                              hipStream_t stream) {
    const float* vert = (const float*)d_in[0];  // [B,3,128,64]
    const float* pc   = (const float*)d_in[1];  // [B,3,8192]
    float* out        = (float*)d_out;
    const int B = in_sizes[0] / (3 * NVERT);

    float* partial = (float*)d_ws;                               // [B,32,MPTS] = 4 MB
    v2f* part = (v2f*)(partial + (size_t)B * NCHUNK * MPTS);     // [B*32]

    dim3 grid(MPTS / BQ, NCHUNK, B);   // 4 x 32 x B = 512 blocks
    minpart_kernel<<<grid, TPB, 0, stream>>>(vert, pc, partial);
    reduce_kernel<<<B * 32, 64, 0, stream>>>(pc, partial, part);
    final_kernel<<<1, 128, 0, stream>>>(part, out, B);
}